// Round 4
// baseline (1039.593 us; speedup 1.0000x reference)
//
#include <hip/hip_runtime.h>
#include <hip/hip_bf16.h>
#include <math.h>

typedef __bf16 bf16;
typedef bf16 bf16x8 __attribute__((ext_vector_type(8)));
typedef bf16 bf16x2 __attribute__((ext_vector_type(2)));
typedef float f32x4 __attribute__((ext_vector_type(4)));

static constexpr int kHID   = 4096;
static constexpr int kB     = 2;
static constexpr int kL     = 2048;
static constexpr int kM     = kB * kL;        // 4096 rows (B*L)
static constexpr int kNKV   = 8;
static constexpr int kNHEAD = 32;
static constexpr int kHD    = 128;
static constexpr int kKVD   = 2 * kNKV * kHD; // 2048

static constexpr float kNegBig = -1.0e30f;

__device__ inline f32x4 mfma16(bf16x8 a, bf16x8 b, f32x4 c) {
  return __builtin_amdgcn_mfma_f32_16x16x32_bf16(a, b, c, 0, 0, 0);
}

// ---------------------------------------------------------------------------
// Dtype probe: read `query` as fp32. If the buffer really holds bf16, the
// bf16 exponent bits of the odd elements land in the fp32 exponent field ->
// |x| ~ 2^100..2^126. If it really holds fp32 N(0,1), max|x| < 6.
// flag = 1 -> buffers are bf16 ; flag = 0 -> buffers are fp32.
// ---------------------------------------------------------------------------
__global__ void detect_k(const float* __restrict__ q, int* __restrict__ flag) {
  float x = fabsf(q[threadIdx.x]);
#pragma unroll
  for (int off = 1; off < 64; off <<= 1) x = fmaxf(x, __shfl_xor(x, off, 64));
  if (threadIdx.x == 0) *flag = (x > 1e10f) ? 1 : 0;
}

// ---------------------------------------------------------------------------
// Convert (or copy) a flat tensor to bf16. n must be divisible by 8.
// ---------------------------------------------------------------------------
__global__ __launch_bounds__(256) void conv_k(const void* __restrict__ in,
                                              bf16* __restrict__ out,
                                              const int* __restrict__ flag,
                                              size_t n) {
  const size_t i = ((size_t)blockIdx.x * 256 + threadIdx.x) * 8;
  if (i >= n) return;
  if (*flag) {
    *(bf16x8*)(out + i) = *(const bf16x8*)((const bf16*)in + i);
  } else {
    const float* f = (const float*)in + i;
    bf16x8 v;
#pragma unroll
    for (int j = 0; j < 8; ++j) v[j] = (bf16)f[j];
    *(bf16x8*)(out + i) = v;
  }
}

// ---------------------------------------------------------------------------
// Convert W[K][N] (row-major, fp32 or bf16 per flag) -> bf16 Wt[N][K].
// ---------------------------------------------------------------------------
__global__ __launch_bounds__(1024) void convT_k(const void* __restrict__ W,
                                                bf16* __restrict__ Wt,
                                                const int* __restrict__ flag,
                                                int K, int N) {
  __shared__ bf16 tile[32][33];
  const int nb = blockIdx.x * 32;
  const int kb = blockIdx.y * 32;
  const int tx = threadIdx.x, ty = threadIdx.y;
  const size_t idx = (size_t)(kb + ty) * N + nb + tx;
  tile[ty][tx] = (*flag) ? ((const bf16*)W)[idx] : (bf16)((const float*)W)[idx];
  __syncthreads();
  Wt[(size_t)(nb + ty) * K + kb + tx] = tile[tx][ty];
}

// ---------------------------------------------------------------------------
// GEMM: C[M][N] = A[M][K] * Bt[N][K]^T + bias[N]. A,Bt bf16; fp32 accumulate.
// 128x128 tile, BK=32, register-round-trip staging with next-tile prefetch.
// bias dtype follows flag. C is bf16 unless (c_flagged && flag==0) -> fp32.
// ---------------------------------------------------------------------------
__global__ __launch_bounds__(256, 2) void gemm_bt_k(const bf16* __restrict__ A,
                                                    const bf16* __restrict__ Bt,
                                                    const void* __restrict__ bias,
                                                    void* __restrict__ C,
                                                    const int* __restrict__ flag,
                                                    int c_flagged,
                                                    int M, int N, int K) {
  __shared__ __align__(16) bf16 As[128 * 32];
  __shared__ __align__(16) bf16 Bs[128 * 32];

  const int fl   = *flag;
  const int tid  = threadIdx.x;
  const int lane = tid & 63;
  const int wave = tid >> 6;
  const int ln   = lane & 15;
  const int quad = lane >> 4;
  const int wr   = wave >> 1;
  const int wc   = wave & 1;
  const size_t mbase = (size_t)blockIdx.y * 128;
  const size_t nbase = (size_t)blockIdx.x * 128;

  const int r0 = tid >> 2, c0 = (tid & 3) * 8;
  const int r1 = (256 + tid) >> 2, c1 = ((256 + tid) & 3) * 8;

  f32x4 acc[4][4];
#pragma unroll
  for (int mt = 0; mt < 4; ++mt)
#pragma unroll
    for (int nt = 0; nt < 4; ++nt)
      acc[mt][nt] = (f32x4){0.f, 0.f, 0.f, 0.f};

  bf16x8 ra0 = *(const bf16x8*)(A  + (mbase + r0) * (size_t)K + c0);
  bf16x8 ra1 = *(const bf16x8*)(A  + (mbase + r1) * (size_t)K + c1);
  bf16x8 rb0 = *(const bf16x8*)(Bt + (nbase + r0) * (size_t)K + c0);
  bf16x8 rb1 = *(const bf16x8*)(Bt + (nbase + r1) * (size_t)K + c1);

#pragma unroll 1
  for (int kb = 0; kb < K; kb += 32) {
    __syncthreads();
    *(bf16x8*)(As + r0 * 32 + c0) = ra0;
    *(bf16x8*)(As + r1 * 32 + c1) = ra1;
    *(bf16x8*)(Bs + r0 * 32 + c0) = rb0;
    *(bf16x8*)(Bs + r1 * 32 + c1) = rb1;
    __syncthreads();

    if (kb + 32 < K) {
      ra0 = *(const bf16x8*)(A  + (mbase + r0) * (size_t)K + kb + 32 + c0);
      ra1 = *(const bf16x8*)(A  + (mbase + r1) * (size_t)K + kb + 32 + c1);
      rb0 = *(const bf16x8*)(Bt + (nbase + r0) * (size_t)K + kb + 32 + c0);
      rb1 = *(const bf16x8*)(Bt + (nbase + r1) * (size_t)K + kb + 32 + c1);
    }

    bf16x8 bfrag[4];
#pragma unroll
    for (int nt = 0; nt < 4; ++nt)
      bfrag[nt] = *(const bf16x8*)(Bs + (wc * 64 + nt * 16 + ln) * 32 + quad * 8);
#pragma unroll
    for (int mt = 0; mt < 4; ++mt) {
      bf16x8 afrag = *(const bf16x8*)(As + (wr * 64 + mt * 16 + ln) * 32 + quad * 8);
#pragma unroll
      for (int nt = 0; nt < 4; ++nt)
        acc[mt][nt] = mfma16(afrag, bfrag[nt], acc[mt][nt]);
    }
  }

  // epilogue. C/D layout: row = quad*4+i, col = ln.
  const int store_f32 = c_flagged && (fl == 0);
#pragma unroll
  for (int nt = 0; nt < 4; ++nt) {
    const size_t col = nbase + wc * 64 + nt * 16 + ln;
    const float bv = fl ? (float)((const bf16*)bias)[col] : ((const float*)bias)[col];
#pragma unroll
    for (int mt = 0; mt < 4; ++mt) {
      const size_t row0 = mbase + wr * 64 + mt * 16 + quad * 4;
#pragma unroll
      for (int i = 0; i < 4; ++i) {
        const float v = acc[mt][nt][i] + bv;
        const size_t off = (row0 + i) * (size_t)N + col;
        if (store_f32) ((float*)C)[off] = v;
        else           ((bf16*)C)[off]  = (bf16)v;
      }
    }
  }
}

// ---------------------------------------------------------------------------
// Flash attention (all-bf16 I/O). One block = (b, head, 128-row Q tile).
// ---------------------------------------------------------------------------
static constexpr int kKVT = 64;
static constexpr int kKP  = 136;
static constexpr int kVP  = 72;

__global__ __launch_bounds__(256, 2) void attn_k(const bf16* __restrict__ Q,
                                                 const bf16* __restrict__ KV,
                                                 bf16* O) {
  __shared__ __align__(16) bf16 Ks[kKVT * kKP];
  __shared__ __align__(16) bf16 Vt[kHD * kVP];
  __shared__ __align__(16) bf16 Ps[128 * kVP];

  const int tid  = threadIdx.x;
  const int lane = tid & 63;
  const int wave = tid >> 6;
  const int ln   = lane & 15;
  const int quad = lane >> 4;
  const int qt   = blockIdx.x;
  const int h    = blockIdx.y;
  const int b    = blockIdx.z;
  const int kvh  = h >> 2;
  const size_t qrowbase = (size_t)b * kL + (size_t)qt * 128;
  const float scale = 0.08838834764831845f;

  bf16x8 qfrag[2][4];
#pragma unroll
  for (int mt = 0; mt < 2; ++mt) {
    const bf16* base = Q + (qrowbase + wave * 32 + mt * 16 + ln) * (size_t)kHID + h * kHD;
#pragma unroll
    for (int kt = 0; kt < 4; ++kt)
      qfrag[mt][kt] = *(const bf16x8*)(base + kt * 32 + quad * 8);
  }

  float m_i[2][4], l_i[2][4];
  f32x4 oacc[2][8];
#pragma unroll
  for (int mt = 0; mt < 2; ++mt)
#pragma unroll
    for (int i = 0; i < 4; ++i) { m_i[mt][i] = kNegBig; l_i[mt][i] = 0.f; }
#pragma unroll
  for (int mt = 0; mt < 2; ++mt)
#pragma unroll
    for (int nt = 0; nt < 8; ++nt)
      oacc[mt][nt] = (f32x4){0.f, 0.f, 0.f, 0.f};

#pragma unroll 1
  for (int kb = 0; kb < kL / kKVT; ++kb) {
    __syncthreads();
#pragma unroll
    for (int it = 0; it < 4; ++it) {
      const int c = it * 256 + tid;
      const int row = c >> 4, cc = c & 15;
      *(bf16x8*)(Ks + row * kKP + cc * 8) =
          *(const bf16x8*)(KV + ((size_t)b * kL + kb * kKVT + row) * kKVD + kvh * kHD + cc * 8);
    }
#pragma unroll
    for (int it = 0; it < 2; ++it) {
      const int p = it * 256 + tid;
      const int rp = p & 31, cc = p >> 5;
      const bf16* vg = KV + ((size_t)b * kL + kb * kKVT + 2 * rp) * kKVD + kNKV * kHD + kvh * kHD + cc * 8;
      bf16x8 v0 = *(const bf16x8*)vg;
      bf16x8 v1 = *(const bf16x8*)(vg + kKVD);
#pragma unroll
      for (int j = 0; j < 8; ++j) {
        bf16x2 pr; pr[0] = v0[j]; pr[1] = v1[j];
        *(bf16x2*)(Vt + (cc * 8 + j) * kVP + 2 * rp) = pr;
      }
    }
    __syncthreads();

    f32x4 sacc[2][4];
#pragma unroll
    for (int mt = 0; mt < 2; ++mt)
#pragma unroll
      for (int nt = 0; nt < 4; ++nt)
        sacc[mt][nt] = (f32x4){0.f, 0.f, 0.f, 0.f};
#pragma unroll
    for (int kt = 0; kt < 4; ++kt) {
#pragma unroll
      for (int nt = 0; nt < 4; ++nt) {
        bf16x8 kfrag = *(const bf16x8*)(Ks + (nt * 16 + ln) * kKP + kt * 32 + quad * 8);
#pragma unroll
        for (int mt = 0; mt < 2; ++mt)
          sacc[mt][nt] = mfma16(qfrag[mt][kt], kfrag, sacc[mt][nt]);
      }
    }

#pragma unroll
    for (int mt = 0; mt < 2; ++mt) {
#pragma unroll
      for (int i = 0; i < 4; ++i) {
        float mx = sacc[mt][0][i];
#pragma unroll
        for (int nt = 1; nt < 4; ++nt) mx = fmaxf(mx, sacc[mt][nt][i]);
#pragma unroll
        for (int off = 1; off < 16; off <<= 1) mx = fmaxf(mx, __shfl_xor(mx, off, 64));
        mx *= scale;
        const float mnew = fmaxf(m_i[mt][i], mx);
        const float alpha = __expf(m_i[mt][i] - mnew);
        float rsum = 0.f;
#pragma unroll
        for (int nt = 0; nt < 4; ++nt) {
          float pv = __expf(sacc[mt][nt][i] * scale - mnew);
          sacc[mt][nt][i] = pv;
          rsum += pv;
        }
#pragma unroll
        for (int off = 1; off < 16; off <<= 1) rsum += __shfl_xor(rsum, off, 64);
        l_i[mt][i] = l_i[mt][i] * alpha + rsum;
        m_i[mt][i] = mnew;
#pragma unroll
        for (int nt = 0; nt < 8; ++nt) oacc[mt][nt][i] *= alpha;
        const int prow = wave * 32 + mt * 16 + quad * 4 + i;
#pragma unroll
        for (int nt = 0; nt < 4; ++nt)
          Ps[prow * kVP + nt * 16 + ln] = (bf16)sacc[mt][nt][i];
      }
    }
    __syncthreads();

#pragma unroll
    for (int kt = 0; kt < 2; ++kt) {
      bf16x8 pfrag[2];
#pragma unroll
      for (int mt = 0; mt < 2; ++mt)
        pfrag[mt] = *(const bf16x8*)(Ps + (wave * 32 + mt * 16 + ln) * kVP + kt * 32 + quad * 8);
#pragma unroll
      for (int nt = 0; nt < 8; ++nt) {
        bf16x8 vfrag = *(const bf16x8*)(Vt + (nt * 16 + ln) * kVP + kt * 32 + quad * 8);
#pragma unroll
        for (int mt = 0; mt < 2; ++mt)
          oacc[mt][nt] = mfma16(pfrag[mt], vfrag, oacc[mt][nt]);
      }
    }
  }

#pragma unroll
  for (int mt = 0; mt < 2; ++mt) {
#pragma unroll
    for (int i = 0; i < 4; ++i) {
      const float inv = 1.0f / l_i[mt][i];
      const size_t row = qrowbase + wave * 32 + mt * 16 + quad * 4 + i;
#pragma unroll
      for (int nt = 0; nt < 8; ++nt)
        O[row * (size_t)kHID + h * kHD + nt * 16 + ln] = (bf16)(oacc[mt][nt][i] * inv);
    }
  }
}

// ---------------------------------------------------------------------------
// ws layout (129 MiB, MiB offsets; lifetimes disjoint under stream order):
//   0       : int flag
//   [1,33)  : qc (bf16 query)      -> Abuf (attn out; qc dead after gemm1)
//   [33,65) : kvc (bf16 kv)
//   [65,97) : WTq                  -> WTo (WTq dead after gemm1)
//   [97,113): WTkv
//   [113,129): KVb
// Q projection lives in d_out (bf16, 32 MiB) until the final GEMM overwrites.
// ---------------------------------------------------------------------------
extern "C" void kernel_launch(void* const* d_in, const int* in_sizes, int n_in,
                              void* d_out, int out_size, void* d_ws, size_t ws_size,
                              hipStream_t stream) {
  const void* query = d_in[0];
  const void* kvin  = d_in[1];
  const void* Wq    = d_in[2];
  const void* bq    = d_in[3];
  const void* Wkv   = d_in[4];
  const void* bkv   = d_in[5];
  const void* Wo    = d_in[6];
  const void* bo    = d_in[7];

  char* ws = (char*)d_ws;
  const size_t MB = 1024 * 1024;
  int*  flag = (int*)ws;
  bf16* qc   = (bf16*)(ws + 1 * MB);
  bf16* Abuf = (bf16*)(ws + 1 * MB);
  bf16* kvc  = (bf16*)(ws + 33 * MB);
  bf16* WTq  = (bf16*)(ws + 65 * MB);
  bf16* WTo  = (bf16*)(ws + 65 * MB);
  bf16* WTkv = (bf16*)(ws + 97 * MB);
  bf16* KVb  = (bf16*)(ws + 113 * MB);
  bf16* Qbuf = (bf16*)d_out;

  const size_t nQ = (size_t)kM * kHID;  // 16.78M

  detect_k<<<1, 64, 0, stream>>>((const float*)query, flag);

  conv_k<<<(int)(nQ / 8 / 256), 256, 0, stream>>>(query, qc, flag, nQ);
  conv_k<<<(int)(nQ / 8 / 256), 256, 0, stream>>>(kvin, kvc, flag, nQ);
  convT_k<<<dim3(kHID / 32, kHID / 32), dim3(32, 32), 0, stream>>>(Wq, WTq, flag, kHID, kHID);
  convT_k<<<dim3(kKVD / 32, kHID / 32), dim3(32, 32), 0, stream>>>(Wkv, WTkv, flag, kHID, kKVD);

  // 1) Q projection -> d_out (bf16)
  gemm_bt_k<<<dim3(kHID / 128, kM / 128), 256, 0, stream>>>(qc, WTq, bq, Qbuf, flag, 0, kM, kHID, kHID);
  // 2) KV projection -> KVb
  gemm_bt_k<<<dim3(kKVD / 128, kM / 128), 256, 0, stream>>>(kvc, WTkv, bkv, KVb, flag, 0, kM, kKVD, kHID);
  // 3) attention -> Abuf (overlays qc, which is dead)
  attn_k<<<dim3(kL / 128, kNHEAD, kB), 256, 0, stream>>>(Qbuf, KVb, Abuf);
  // 4) output projection -> d_out (dtype per flag)
  convT_k<<<dim3(kHID / 32, kHID / 32), dim3(32, 32), 0, stream>>>(Wo, WTo, flag, kHID, kHID);
  gemm_bt_k<<<dim3(kHID / 128, kM / 128), 256, 0, stream>>>(Abuf, WTo, bo, d_out, flag, 1, kM, kHID, kHID);
}